// Round 6
// baseline (993.007 us; speedup 1.0000x reference)
//
#include <hip/hip_runtime.h>

// DPP helper (builtin path: direction probe only)
#define ROTI(v, CTRL) __builtin_amdgcn_update_dpp(0, (v), (CTRL), 0xF, 0xF, true)

constexpr int T_LEN  = 8192;
constexpr int BATCH  = 256;
constexpr int HID    = 16;
constexpr int RING   = 64;    // ring slots (timesteps) in LDS
constexpr int SLOT_W = 129;   // words/slot: 8 batches*16 + 1 pad (stride ≡ 1 mod 32)

// One position = one step of BOTH streams A,B, fully hand-scheduled.
// - 1:1 A/B interleave: every dependent op has >=2 insts (4cy) of the other
//   stream between it and its producer; tanh trans-chain latency is hidden.
// - 2 accumulator chains per stream (even/odd rotations), reuse gap 4 insts.
// - Hazards: s_nop 1 + 2 plain fmacs before first DPP read of h (VALU->DPP
//   needs 2 wait states); h written 3rd-to-last inst, next DPP read of it is
//   >=7 insts later (2 ds_write + 2 fma outside + s_nop + 2 fmac).
// - Weights pre-scaled by 2*log2(e): chain is sum -> exp2 -> +1 -> rcp -> fma.
#define STEP2(aA0_, aB0_, hA_, hB_)                                                    \
  asm("s_nop 1\n\t"                                                                    \
      "v_fmac_f32 %[aA0], %[hA], %[w0]\n\t"                                            \
      "v_fmac_f32 %[aB0], %[hB], %[w0]\n\t"                                            \
      "v_mul_f32_dpp %[aA1], %[hA], %[w1] row_ror:1 row_mask:0xf bank_mask:0xf\n\t"    \
      "v_mul_f32_dpp %[aB1], %[hB], %[w1] row_ror:1 row_mask:0xf bank_mask:0xf\n\t"    \
      "v_fmac_f32_dpp %[aA0], %[hA], %[w2] row_ror:2 row_mask:0xf bank_mask:0xf\n\t"   \
      "v_fmac_f32_dpp %[aB0], %[hB], %[w2] row_ror:2 row_mask:0xf bank_mask:0xf\n\t"   \
      "v_fmac_f32_dpp %[aA1], %[hA], %[w3] row_ror:3 row_mask:0xf bank_mask:0xf\n\t"   \
      "v_fmac_f32_dpp %[aB1], %[hB], %[w3] row_ror:3 row_mask:0xf bank_mask:0xf\n\t"   \
      "v_fmac_f32_dpp %[aA0], %[hA], %[w4] row_ror:4 row_mask:0xf bank_mask:0xf\n\t"   \
      "v_fmac_f32_dpp %[aB0], %[hB], %[w4] row_ror:4 row_mask:0xf bank_mask:0xf\n\t"   \
      "v_fmac_f32_dpp %[aA1], %[hA], %[w5] row_ror:5 row_mask:0xf bank_mask:0xf\n\t"   \
      "v_fmac_f32_dpp %[aB1], %[hB], %[w5] row_ror:5 row_mask:0xf bank_mask:0xf\n\t"   \
      "v_fmac_f32_dpp %[aA0], %[hA], %[w6] row_ror:6 row_mask:0xf bank_mask:0xf\n\t"   \
      "v_fmac_f32_dpp %[aB0], %[hB], %[w6] row_ror:6 row_mask:0xf bank_mask:0xf\n\t"   \
      "v_fmac_f32_dpp %[aA1], %[hA], %[w7] row_ror:7 row_mask:0xf bank_mask:0xf\n\t"   \
      "v_fmac_f32_dpp %[aB1], %[hB], %[w7] row_ror:7 row_mask:0xf bank_mask:0xf\n\t"   \
      "v_fmac_f32_dpp %[aA0], %[hA], %[w8] row_ror:8 row_mask:0xf bank_mask:0xf\n\t"   \
      "v_fmac_f32_dpp %[aB0], %[hB], %[w8] row_ror:8 row_mask:0xf bank_mask:0xf\n\t"   \
      "v_fmac_f32_dpp %[aA1], %[hA], %[w9] row_ror:9 row_mask:0xf bank_mask:0xf\n\t"   \
      "v_fmac_f32_dpp %[aB1], %[hB], %[w9] row_ror:9 row_mask:0xf bank_mask:0xf\n\t"   \
      "v_fmac_f32_dpp %[aA0], %[hA], %[w10] row_ror:10 row_mask:0xf bank_mask:0xf\n\t" \
      "v_fmac_f32_dpp %[aB0], %[hB], %[w10] row_ror:10 row_mask:0xf bank_mask:0xf\n\t" \
      "v_fmac_f32_dpp %[aA1], %[hA], %[w11] row_ror:11 row_mask:0xf bank_mask:0xf\n\t" \
      "v_fmac_f32_dpp %[aB1], %[hB], %[w11] row_ror:11 row_mask:0xf bank_mask:0xf\n\t" \
      "v_fmac_f32_dpp %[aA0], %[hA], %[w12] row_ror:12 row_mask:0xf bank_mask:0xf\n\t" \
      "v_fmac_f32_dpp %[aB0], %[hB], %[w12] row_ror:12 row_mask:0xf bank_mask:0xf\n\t" \
      "v_fmac_f32_dpp %[aA1], %[hA], %[w13] row_ror:13 row_mask:0xf bank_mask:0xf\n\t" \
      "v_fmac_f32_dpp %[aB1], %[hB], %[w13] row_ror:13 row_mask:0xf bank_mask:0xf\n\t" \
      "v_fmac_f32_dpp %[aA0], %[hA], %[w14] row_ror:14 row_mask:0xf bank_mask:0xf\n\t" \
      "v_fmac_f32_dpp %[aB0], %[hB], %[w14] row_ror:14 row_mask:0xf bank_mask:0xf\n\t" \
      "v_fmac_f32_dpp %[aA1], %[hA], %[w15] row_ror:15 row_mask:0xf bank_mask:0xf\n\t" \
      "v_fmac_f32_dpp %[aB1], %[hB], %[w15] row_ror:15 row_mask:0xf bank_mask:0xf\n\t" \
      "v_add_f32 %[aA0], %[aA0], %[aA1]\n\t"                                           \
      "v_add_f32 %[aB0], %[aB0], %[aB1]\n\t"                                           \
      "v_exp_f32 %[aA1], %[aA0]\n\t"                                                   \
      "v_exp_f32 %[aB1], %[aB0]\n\t"                                                   \
      "v_add_f32 %[aA0], 1.0, %[aA1]\n\t"                                              \
      "v_add_f32 %[aB0], 1.0, %[aB1]\n\t"                                              \
      "v_rcp_f32 %[aA1], %[aA0]\n\t"                                                   \
      "v_rcp_f32 %[aB1], %[aB0]\n\t"                                                   \
      "v_fma_f32 %[hA], -2.0, %[aA1], 1.0\n\t"                                         \
      "v_fma_f32 %[hB], -2.0, %[aB1], 1.0\n\t"                                         \
      : [aA0]"+v"(aA0_), [aB0]"+v"(aB0_),                                              \
        [aA1]"=&v"(tmpA), [aB1]"=&v"(tmpB),                                            \
        [hA]"+v"(hA_), [hB]"+v"(hB_)                                                   \
      : [w0]"v"(wr0),  [w1]"v"(wr1),  [w2]"v"(wr2),  [w3]"v"(wr3),                     \
        [w4]"v"(wr4),  [w5]"v"(wr5),  [w6]"v"(wr6),  [w7]"v"(wr7),                     \
        [w8]"v"(wr8),  [w9]"v"(wr9),  [w10]"v"(wr10), [w11]"v"(wr11),                  \
        [w12]"v"(wr12), [w13]"v"(wr13), [w14]"v"(wr14), [w15]"v"(wr15))

// One position: init accumulators (x-projection), run both streams, store h
// to the ring. POS is a compile-time literal -> immediate ds_write offsets.
#define POSITION(XA, XB, POS) do {                                                     \
    float aA0 = fmaf((XA), wihK, biasK);                                               \
    float aB0 = fmaf((XB), wihK, biasK);                                               \
    STEP2(aA0, aB0, hA, hB);                                                           \
    rp[(POS) * SLOT_W]      = hA;                                                      \
    rp[(POS) * SLOT_W + 64] = hB;                                                      \
} while (0)

__global__ void __launch_bounds__(128, 1)
rnn_fused(const float* __restrict__ x,
          const float* __restrict__ hinit,
          const float* __restrict__ Wih,
          const float* __restrict__ Whh,
          const float* __restrict__ bih,
          const float* __restrict__ bhh,
          const float* __restrict__ Wout,
          const float* __restrict__ boutp,
          float* __restrict__ out)
{
    __shared__ float ring[RING * SLOT_W];
    __shared__ int   syncc[2];
    volatile int* prodc = &syncc[0];
    volatile int* consc = &syncc[1];

    const int tid = (int)threadIdx.x;
    if (tid == 0) { syncc[0] = 0; syncc[1] = 0; }
    __syncthreads();

    if (tid < 64) {
        // ---------------- producer wave: the serial recurrence ----------------
        const int j = tid & 15;          // hidden index this lane owns
        const int g = tid >> 4;          // batch sub-index 0..3
        const int bA = (int)blockIdx.x * 8 + g;      // stream A batch
        const int bB = bA + 4;                       // stream B batch

        // DPP row_ror direction probe (passed rounds 1-5)
        const int pr  = ROTI(j, 0x121);
        const int dir = (__builtin_amdgcn_readfirstlane(pr) == 1) ? 1 : -1;

        const float K2 = 2.8853900817779268f;   // 2*log2(e), folded into weights
        float wr0  = K2 * Whh[j * HID + ((j + dir * 0)  & 15)];
        float wr1  = K2 * Whh[j * HID + ((j + dir * 1)  & 15)];
        float wr2  = K2 * Whh[j * HID + ((j + dir * 2)  & 15)];
        float wr3  = K2 * Whh[j * HID + ((j + dir * 3)  & 15)];
        float wr4  = K2 * Whh[j * HID + ((j + dir * 4)  & 15)];
        float wr5  = K2 * Whh[j * HID + ((j + dir * 5)  & 15)];
        float wr6  = K2 * Whh[j * HID + ((j + dir * 6)  & 15)];
        float wr7  = K2 * Whh[j * HID + ((j + dir * 7)  & 15)];
        float wr8  = K2 * Whh[j * HID + ((j + dir * 8)  & 15)];
        float wr9  = K2 * Whh[j * HID + ((j + dir * 9)  & 15)];
        float wr10 = K2 * Whh[j * HID + ((j + dir * 10) & 15)];
        float wr11 = K2 * Whh[j * HID + ((j + dir * 11) & 15)];
        float wr12 = K2 * Whh[j * HID + ((j + dir * 12) & 15)];
        float wr13 = K2 * Whh[j * HID + ((j + dir * 13) & 15)];
        float wr14 = K2 * Whh[j * HID + ((j + dir * 14) & 15)];
        float wr15 = K2 * Whh[j * HID + ((j + dir * 15) & 15)];

        const float wihK  = K2 * Wih[j];
        const float biasK = K2 * (bih[j] + bhh[j]);

        float hA = hinit[bA * HID + j];
        float hB = hinit[bB * HID + j];
        float tmpA, tmpB;                        // asm scratch

        const float* xbA = x + (size_t)bA * T_LEN;
        const float* xbB = x + (size_t)bB * T_LEN;

        float4 qA0 = ((const float4*)xbA)[0], qA1 = ((const float4*)xbA)[1],
               qA2 = ((const float4*)xbA)[2], qA3 = ((const float4*)xbA)[3];
        float4 qB0 = ((const float4*)xbB)[0], qB1 = ((const float4*)xbB)[1],
               qB2 = ((const float4*)xbB)[2], qB3 = ((const float4*)xbB)[3];

        for (int t0 = 0; t0 < T_LEN; t0 += 16) {
            // ring-slot reuse guard (slots for t0..t0+15 freed by consumer)
            const int need = t0 + 16 - RING;
            if (need > 0) {
                while (*consc < need) { }
                __asm__ volatile("" ::: "memory");
            }
            // prefetch next 16 x values per stream (wraps harmlessly at end)
            const int tn = (t0 + 16) & (T_LEN - 1);
            const float* qa = xbA + tn;
            const float* qb = xbB + tn;
            float4 nA0 = ((const float4*)qa)[0], nA1 = ((const float4*)qa)[1],
                   nA2 = ((const float4*)qa)[2], nA3 = ((const float4*)qa)[3];
            float4 nB0 = ((const float4*)qb)[0], nB1 = ((const float4*)qb)[1],
                   nB2 = ((const float4*)qb)[2], nB3 = ((const float4*)qb)[3];

            float* rp = &ring[(t0 & (RING - 1)) * SLOT_W + g * 16 + j];

            POSITION(qA0.x, qB0.x, 0);
            POSITION(qA0.y, qB0.y, 1);
            POSITION(qA0.z, qB0.z, 2);
            POSITION(qA0.w, qB0.w, 3);
            POSITION(qA1.x, qB1.x, 4);
            POSITION(qA1.y, qB1.y, 5);
            POSITION(qA1.z, qB1.z, 6);
            POSITION(qA1.w, qB1.w, 7);
            POSITION(qA2.x, qB2.x, 8);
            POSITION(qA2.y, qB2.y, 9);
            POSITION(qA2.z, qB2.z, 10);
            POSITION(qA2.w, qB2.w, 11);
            POSITION(qA3.x, qB3.x, 12);
            POSITION(qA3.y, qB3.y, 13);
            POSITION(qA3.z, qB3.z, 14);
            POSITION(qA3.w, qB3.w, 15);

            qA0 = nA0; qA1 = nA1; qA2 = nA2; qA3 = nA3;
            qB0 = nB0; qB1 = nB1; qB2 = nB2; qB3 = nB3;

            // publish completed steps (drain ds_writes first)
            __asm__ volatile("s_waitcnt lgkmcnt(0)" ::: "memory");
            *prodc = t0 + 16;
        }

        // final hidden state hT [1,B,H]
        out[(size_t)BATCH * T_LEN + (size_t)bA * HID + j] = hA;
        out[(size_t)BATCH * T_LEN + (size_t)bB * HID + j] = hB;
    } else {
        // -------------- consumer wave: output projection + stores --------------
        const int lane = tid - 64;        // 0..63
        const int tt   = lane & 15;       // timestep offset within chunk
        const int bs   = lane >> 4;       // batch sub-index 0..3
        const int bgA  = (int)blockIdx.x * 8 + bs;   // stream A batch
        const int bgB  = bgA + 4;                    // stream B batch

        const float w0  = Wout[0],  w1  = Wout[1],  w2  = Wout[2],  w3  = Wout[3];
        const float w4  = Wout[4],  w5  = Wout[5],  w6  = Wout[6],  w7  = Wout[7];
        const float w8  = Wout[8],  w9  = Wout[9],  w10 = Wout[10], w11 = Wout[11];
        const float w12 = Wout[12], w13 = Wout[13], w14 = Wout[14], w15 = Wout[15];
        const float bo  = boutp[0];

        float* obA = out + (size_t)bgA * T_LEN;
        float* obB = out + (size_t)bgB * T_LEN;

        for (int t0 = 0; t0 < T_LEN; t0 += 16) {
            while (*prodc < t0 + 16) { }
            __asm__ volatile("" ::: "memory");

            // bank-conflict-free: addr = slot*129 + {0|64} + bs*16 + k
            // -> bank = (tt + 16*bs + k) % 32, 2 lanes/bank (free)
            const float* base = &ring[((t0 + tt) & (RING - 1)) * SLOT_W + bs * 16];
            {
                const float* hr = base;
                float o = bo;
                o = fmaf(hr[0],  w0,  o); o = fmaf(hr[1],  w1,  o);
                o = fmaf(hr[2],  w2,  o); o = fmaf(hr[3],  w3,  o);
                o = fmaf(hr[4],  w4,  o); o = fmaf(hr[5],  w5,  o);
                o = fmaf(hr[6],  w6,  o); o = fmaf(hr[7],  w7,  o);
                o = fmaf(hr[8],  w8,  o); o = fmaf(hr[9],  w9,  o);
                o = fmaf(hr[10], w10, o); o = fmaf(hr[11], w11, o);
                o = fmaf(hr[12], w12, o); o = fmaf(hr[13], w13, o);
                o = fmaf(hr[14], w14, o); o = fmaf(hr[15], w15, o);
                obA[t0 + tt] = o;
            }
            {
                const float* hr = base + 64;
                float o = bo;
                o = fmaf(hr[0],  w0,  o); o = fmaf(hr[1],  w1,  o);
                o = fmaf(hr[2],  w2,  o); o = fmaf(hr[3],  w3,  o);
                o = fmaf(hr[4],  w4,  o); o = fmaf(hr[5],  w5,  o);
                o = fmaf(hr[6],  w6,  o); o = fmaf(hr[7],  w7,  o);
                o = fmaf(hr[8],  w8,  o); o = fmaf(hr[9],  w9,  o);
                o = fmaf(hr[10], w10, o); o = fmaf(hr[11], w11, o);
                o = fmaf(hr[12], w12, o); o = fmaf(hr[13], w13, o);
                o = fmaf(hr[14], w14, o); o = fmaf(hr[15], w15, o);
                obB[t0 + tt] = o;
            }

            *consc = t0 + 16;                      // release ring slots
        }
    }
}

extern "C" void kernel_launch(void* const* d_in, const int* in_sizes, int n_in,
                              void* d_out, int out_size, void* d_ws, size_t ws_size,
                              hipStream_t stream)
{
    const float* x    = (const float*)d_in[0];
    const float* h0   = (const float*)d_in[1];
    const float* Wih  = (const float*)d_in[2];
    const float* Whh  = (const float*)d_in[3];
    const float* bih  = (const float*)d_in[4];
    const float* bhh  = (const float*)d_in[5];
    const float* Wout = (const float*)d_in[6];
    const float* bout = (const float*)d_in[7];
    float* out = (float*)d_out;

    rnn_fused<<<dim3(BATCH / 8), dim3(128), 0, stream>>>(
        x, h0, Wih, Whh, bih, bhh, Wout, bout, out);
}

// Round 9
// 592.255 us; speedup vs baseline: 1.6767x; 1.6767x over previous
//
#include <hip/hip_runtime.h>

// Match the builtin's native v2fp16 type exactly
typedef decltype(__builtin_amdgcn_cvt_pkrtz(0.0f, 0.0f)) h2;

// DPP rotate within 16-lane rows: CTRL = 0x120 + r (row_ror:r)
#define DPPI(v, CTRL) __builtin_amdgcn_update_dpp(0, (v), (CTRL), 0xF, 0xF, true)
#define H2(x)  __builtin_bit_cast(h2, (x))
#define I32(x) __builtin_bit_cast(int, (x))

constexpr int T_LEN  = 8192;
constexpr int BATCH  = 256;
constexpr int HID    = 16;
constexpr int RING   = 64;    // ring slots (timesteps) in LDS
constexpr int SLOT_W = 67;    // words per slot (odd stride -> <=2-way banks, free)

// reciprocal via magic + 2 Newton iterations (avoids the v_rcp TRANS op).
// d in [1, 2^20]; rel err ~0.05 -> 6e-6 after 2 NR.
__device__ __forceinline__ float rcp_nr(float d) {
    float r = __int_as_float(0x7EF311C3 - __float_as_int(d));
    r = r * fmaf(-d, r, 2.0f);
    r = r * fmaf(-d, r, 2.0f);
    return r;
}

// One recurrence step (weights pre-scaled by 2*log2e):
//   rotate packed pair P by even amounts (7 DPP), 8x fdot2 (2 chains),
//   tanh via exp2 + NR-rcp, then rebuild P = pkrtz(h_j, h_{j+dir}).
#define STEP(XV, KOFF) do {                                                   \
    int q1 = DPPI(Pi, 0x122), q2 = DPPI(Pi, 0x124), q3 = DPPI(Pi, 0x126);     \
    int q4 = DPPI(Pi, 0x128), q5 = DPPI(Pi, 0x12A), q6 = DPPI(Pi, 0x12C);     \
    int q7 = DPPI(Pi, 0x12E);                                                 \
    float a0 = fmaf((XV), wihK, biasK);                                       \
    a0 = __builtin_amdgcn_fdot2(H2(Pi), w0, a0, false);                       \
    a0 = __builtin_amdgcn_fdot2(H2(q1), w1, a0, false);                       \
    a0 = __builtin_amdgcn_fdot2(H2(q2), w2, a0, false);                       \
    a0 = __builtin_amdgcn_fdot2(H2(q3), w3, a0, false);                       \
    float a1 = __builtin_amdgcn_fdot2(H2(q4), w4, 0.0f, false);               \
    a1 = __builtin_amdgcn_fdot2(H2(q5), w5, a1, false);                       \
    a1 = __builtin_amdgcn_fdot2(H2(q6), w6, a1, false);                       \
    a1 = __builtin_amdgcn_fdot2(H2(q7), w7, a1, false);                       \
    float e  = __builtin_amdgcn_exp2f(a0 + a1);                               \
    float dd = e + 1.0f;                                                      \
    float r  = rcp_nr(dd);                                                    \
    h = fmaf(-2.0f, r, 1.0f);                                                 \
    int hn = DPPI(__float_as_int(h), 0x121);                                  \
    Pi = I32(__builtin_amdgcn_cvt_pkrtz(h, __int_as_float(hn)));              \
    rbase[(KOFF) * SLOT_W] = Pi;                                              \
} while (0)

__global__ void __launch_bounds__(128, 1)
rnn_fused(const float* __restrict__ x,
          const float* __restrict__ hinit,
          const float* __restrict__ Wih,
          const float* __restrict__ Whh,
          const float* __restrict__ bih,
          const float* __restrict__ bhh,
          const float* __restrict__ Wout,
          const float* __restrict__ boutp,
          float* __restrict__ out)
{
    __shared__ int ring[RING * SLOT_W];
    __shared__ int syncc[2];
    volatile int* prodc = &syncc[0];
    volatile int* consc = &syncc[1];

    const int tid = (int)threadIdx.x;
    if (tid == 0) { syncc[0] = 0; syncc[1] = 0; }
    __syncthreads();

    if (tid < 64) {
        // ---------------- producer wave: the serial recurrence ----------------
        const int j = tid & 15;          // hidden index this lane owns
        const int g = tid >> 4;          // batch sub-index 0..3
        const int b = (int)blockIdx.x * 4 + g;

        // DPP row_ror direction probe (passed rounds 1-6): arriving value at
        // rotation r is h[(j + dir*r) & 15].
        const int pr  = DPPI(j, 0x121);
        const int dir = (__builtin_amdgcn_readfirstlane(pr) == 1) ? 1 : -1;

        const float K2 = 2.8853900817779268f;   // 2*log2(e), folded into weights

        // Packed f16 weight pairs: rotation q (ror:2q) delivers pair
        // (h[j+dir*2q], h[j+dir*(2q+1)]) -> weight pair matches.
        h2 w0, w1, w2, w3, w4, w5, w6, w7;
        {
#define PACKW(Q, DST) do {                                                    \
            float lo = K2 * Whh[j * HID + ((j + dir * (2 * (Q)))     & 15)];  \
            float hi = K2 * Whh[j * HID + ((j + dir * (2 * (Q) + 1)) & 15)];  \
            DST = __builtin_amdgcn_cvt_pkrtz(lo, hi);                         \
        } while (0)
            PACKW(0, w0); PACKW(1, w1); PACKW(2, w2); PACKW(3, w3);
            PACKW(4, w4); PACKW(5, w5); PACKW(6, w6); PACKW(7, w7);
#undef PACKW
        }

        const float wihK  = K2 * Wih[j];
        const float biasK = K2 * (bih[j] + bhh[j]);

        float h = hinit[b * HID + j];
        // initial packed pair P = (h_j, h_{j+dir})
        int hn0 = DPPI(__float_as_int(h), 0x121);
        int Pi  = I32(__builtin_amdgcn_cvt_pkrtz(h, __int_as_float(hn0)));

        const float* xb = x + (size_t)b * T_LEN;
        float4 c0 = ((const float4*)xb)[0], c1 = ((const float4*)xb)[1],
               c2 = ((const float4*)xb)[2], c3 = ((const float4*)xb)[3];

        for (int t0 = 0; t0 < T_LEN; t0 += 16) {
            // ring-slot reuse guard
            const int need = t0 + 16 - RING;
            if (need > 0) {
                while (*consc < need) { }
                __asm__ volatile("" ::: "memory");
            }
            // prefetch next 16 x values (wraps harmlessly on last iter)
            const int tn = (t0 + 16) & (T_LEN - 1);
            const float* q = xb + tn;
            float4 n0 = ((const float4*)q)[0], n1 = ((const float4*)q)[1],
                   n2 = ((const float4*)q)[2], n3 = ((const float4*)q)[3];

            int* rbase = &ring[(t0 & (RING - 1)) * SLOT_W + g * 16 + j];

            STEP(c0.x, 0);  STEP(c0.y, 1);  STEP(c0.z, 2);  STEP(c0.w, 3);
            STEP(c1.x, 4);  STEP(c1.y, 5);  STEP(c1.z, 6);  STEP(c1.w, 7);
            STEP(c2.x, 8);  STEP(c2.y, 9);  STEP(c2.z, 10); STEP(c2.w, 11);
            STEP(c3.x, 12); STEP(c3.y, 13); STEP(c3.z, 14); STEP(c3.w, 15);

            c0 = n0; c1 = n1; c2 = n2; c3 = n3;

            // publish completed steps (drain ds_writes first)
            __asm__ volatile("s_waitcnt lgkmcnt(0)" ::: "memory");
            *prodc = t0 + 16;
        }

        // final hidden state hT [1,B,H] (f32, exact register value)
        out[(size_t)BATCH * T_LEN + (size_t)b * HID + j] = h;
    } else {
        // -------------- consumer wave: output projection + stores --------------
        const int lane = tid - 64;        // 0..63
        const int tt   = lane & 15;       // timestep offset within chunk
        const int bs   = lane >> 4;       // batch sub-index 0..3
        const int bg   = (int)blockIdx.x * 4 + bs;

        // own direction probe (different wave)
        const int pr  = DPPI(lane & 15, 0x121);
        const int dir = (__builtin_amdgcn_readfirstlane(pr) == 1) ? 1 : -1;

        // wout pairs matching P_j = (h_j, h_{j+dir}) for even j = 2q
        h2 u0, u1, u2, u3, u4, u5, u6, u7;
#define PACKU(Q, DST) do {                                                    \
        float lo = Wout[2 * (Q)];                                             \
        float hi = Wout[(2 * (Q) + dir) & 15];                                \
        DST = __builtin_amdgcn_cvt_pkrtz(lo, hi);                             \
    } while (0)
        PACKU(0, u0); PACKU(1, u1); PACKU(2, u2); PACKU(3, u3);
        PACKU(4, u4); PACKU(5, u5); PACKU(6, u6); PACKU(7, u7);
#undef PACKU
        const float bo = boutp[0];

        float* ob = out + (size_t)bg * T_LEN;

        for (int t0 = 0; t0 < T_LEN; t0 += 16) {
            while (*prodc < t0 + 16) { }
            __asm__ volatile("" ::: "memory");

            const int* rr = &ring[((t0 + tt) & (RING - 1)) * SLOT_W + bs * 16];
            float o = bo;
            o = __builtin_amdgcn_fdot2(H2(rr[0]),  u0, o, false);
            o = __builtin_amdgcn_fdot2(H2(rr[2]),  u1, o, false);
            o = __builtin_amdgcn_fdot2(H2(rr[4]),  u2, o, false);
            o = __builtin_amdgcn_fdot2(H2(rr[6]),  u3, o, false);
            o = __builtin_amdgcn_fdot2(H2(rr[8]),  u4, o, false);
            o = __builtin_amdgcn_fdot2(H2(rr[10]), u5, o, false);
            o = __builtin_amdgcn_fdot2(H2(rr[12]), u6, o, false);
            o = __builtin_amdgcn_fdot2(H2(rr[14]), u7, o, false);
            ob[t0 + tt] = o;                 // coalesced 16-wide per group

            if (lane == 0) *consc = t0 + 16; // release ring slots
        }
    }
}

extern "C" void kernel_launch(void* const* d_in, const int* in_sizes, int n_in,
                              void* d_out, int out_size, void* d_ws, size_t ws_size,
                              hipStream_t stream)
{
    const float* x    = (const float*)d_in[0];
    const float* h0   = (const float*)d_in[1];
    const float* Wih  = (const float*)d_in[2];
    const float* Whh  = (const float*)d_in[3];
    const float* bih  = (const float*)d_in[4];
    const float* bhh  = (const float*)d_in[5];
    const float* Wout = (const float*)d_in[6];
    const float* bout = (const float*)d_in[7];
    float* out = (float*)d_out;

    rnn_fused<<<dim3(BATCH / 4), dim3(128), 0, stream>>>(
        x, h0, Wih, Whh, bih, bhh, Wout, bout, out);
}